// Round 1
// 4349.112 us; speedup vs baseline: 1.4520x; 1.4520x over previous
//
#include <hip/hip_runtime.h>
#include <hip/hip_bf16.h>

typedef __bf16 bf16_t;
typedef bf16_t bf16x8 __attribute__((ext_vector_type(8)));
typedef float f32x4 __attribute__((ext_vector_type(4)));
typedef unsigned long long u64;

#define T_SEQ 512
#define NB 128
#define HID 1024
#define FIN 64
#define LD0 1088                 // 64 + 1024
#define LD1 2048                 // 1024 + 1024
#define HB (NB * HID)            // 131072 elems = 256 KB per h snapshot
#define ST0 1096                 // L0 LDS weight row stride (elems, K=1088)
#define STX 1032                 // X1/L1 LDS weight row stride (elems, K=1024)
#define NBLK 256                 // 64 L0 + 64 X1 + 128 L1  (all 256 CUs)
#define DM 32                    // master h ring depth
#define DX 8                     // X1 partial ring depth (2 MB f32 / slot)
#define X1SLOT (4096 * NB)       // floats per X1 slot: [4096 gate-rows][128 batch]
#define LDS_BYTES (64 * ST0 * 2 + 4096)   // max over roles (L0)

// sync[]: per-block completion flags (value = steps completed).
#define F0 0      // f0[64]:  L0 block flags
#define FX 64     // fX[64]:  X1 block flags
#define F1 128    // f1[128]: L1 block flags
#define SYNC_N 256

__device__ __forceinline__ float sigm_f(float x) { return 1.0f / (1.0f + __expf(-x)); }
__device__ __forceinline__ float tanh_f(float x) { return 2.0f * sigm_f(2.0f * x) - 1.0f; }

__device__ __forceinline__ unsigned ldcnt(const unsigned* p) {
    return __hip_atomic_load(p, __ATOMIC_RELAXED, __HIP_MEMORY_SCOPE_AGENT);
}
__device__ __forceinline__ void stw32(unsigned* p, unsigned v) {   // write-through
    __hip_atomic_store(p, v, __ATOMIC_RELAXED, __HIP_MEMORY_SCOPE_AGENT);
}
__device__ __forceinline__ void stwf(float* p, float v) {          // write-through f32
    __hip_atomic_store(p, v, __ATOMIC_RELAXED, __HIP_MEMORY_SCOPE_AGENT);
}
__device__ __forceinline__ void stw64(u64* p, u64 v) {
    __hip_atomic_store(p, v, __ATOMIC_RELAXED, __HIP_MEMORY_SCOPE_AGENT);
}

// Fragment-swizzled h layout: 16B unit = (panel*8 + wv)*64 + lane, holding
// h[n = wv*16 + (lane&15)][k = panel*32 + (lane>>4)*8 .. +8].

__global__ __launch_bounds__(256) void prep_kernel(
    const float* __restrict__ x,
    const float* __restrict__ Wih0, const float* __restrict__ Whh0,
    const float* __restrict__ bih0, const float* __restrict__ bhh0,
    const float* __restrict__ Wih1, const float* __restrict__ Whh1,
    const float* __restrict__ bih1, const float* __restrict__ bhh1,
    const float* __restrict__ Wfc,
    bf16_t* __restrict__ Wcat0, bf16_t* __restrict__ Wcat1,
    bf16_t* __restrict__ xswz, bf16_t* __restrict__ Wfcb,
    float* __restrict__ bias0, float* __restrict__ bias1,
    bf16_t* __restrict__ mh0, bf16_t* __restrict__ mh1,
    float* __restrict__ c0, float* __restrict__ c1,
    unsigned* __restrict__ sync)
{
    const unsigned stride = gridDim.x * blockDim.x;
    const unsigned i0 = blockIdx.x * blockDim.x + threadIdx.x;

    for (unsigned i = i0; i < SYNC_N; i += stride) sync[i] = 0u;

    for (unsigned i = i0; i < 4096u * LD1; i += stride) {
        unsigned m = i >> 11, kk = i & 2047u;
        float v = (kk < HID) ? Wih1[m * HID + kk] : Whh1[m * HID + (kk - HID)];
        Wcat1[i] = (bf16_t)v;
    }
    for (unsigned i = i0; i < 4096u * LD0; i += stride) {
        unsigned m = i / LD0, kk = i - m * LD0;
        float v = (kk < FIN) ? Wih0[m * FIN + kk] : Whh0[m * HID + (kk - FIN)];
        Wcat0[i] = (bf16_t)v;
    }
    // x into fragment-swizzled layout
    for (unsigned i = i0; i < 4194304u; i += stride) {   // 128*512*64
        unsigned e = i & 7u, unit = i >> 3;
        unsigned lane = unit & 63u, g = unit >> 6;
        unsigned wvv = g & 7u, pt = g >> 3;              // pt = t*2 + p
        unsigned p = pt & 1u, t = pt >> 1;
        unsigned n = wvv * 16u + (lane & 15u);
        unsigned k = p * 32u + (lane >> 4) * 8u + e;
        xswz[i] = (bf16_t)x[((size_t)n * T_SEQ + t) * FIN + k];
    }
    for (unsigned i = i0; i < 64u * HID; i += stride)
        Wfcb[i] = (bf16_t)Wfc[i];
    for (unsigned i = i0; i < (unsigned)(DM * HB); i += stride) {
        mh0[i] = (bf16_t)0.0f; mh1[i] = (bf16_t)0.0f;    // slot DM-1 read as h[-1]=0
    }
    for (unsigned i = i0; i < (unsigned)HB; i += stride) { c0[i] = 0.0f; c1[i] = 0.0f; }
    for (unsigned i = i0; i < 4096u; i += stride) {
        bias0[i] = bih0[i] + bhh0[i];
        bias1[i] = bih1[i] + bhh1[i];
    }
}

// Persistent cooperative kernel: 256 blocks x 512 threads, 1 block/CU.
// Blocks 0..63   = L0: recurrence of layer 0 (rows=16 units x 4 gates, K=1088).
// Blocks 64..127 = X1: input-half partials of layer 1, W_ih1 @ h0[t]
//                  (rows=16 units x 4 gates, K=1024) -> f32 ring, DX deep.
//                  Runs ~DX steps ahead of L1 (pipelined off the chain).
// Blocks 128..255= L1: recurrent half only, acc init from X1 partials
//                  (rows=8 units x 4 gates, K=1024).
// Producers write rings with write-through atomics; consumers use PLAIN
// coalesced loads (XCD L2 aggregates; ring depth >> L2 slot lifetime).
__global__ __launch_bounds__(512) void lstm_persist(
    const bf16_t* __restrict__ Wcat0, const bf16_t* __restrict__ Wcat1,
    const float* __restrict__ bias0, const float* __restrict__ bias1,
    const bf16_t* __restrict__ xswz,
    bf16_t* __restrict__ mh0,   // [DM][HB] master h0 ring (swizzled)
    bf16_t* __restrict__ mh1,   // [DM][HB] master h1 ring (swizzled)
    float* __restrict__ c0, float* __restrict__ c1,   // [HID][NB], block-private
    bf16_t* __restrict__ h2buf, // [NB][T][HID] layer1 history for FC
    float* __restrict__ x1r,    // [DX][4096][NB] f32 partial preactivation ring
    unsigned* __restrict__ sync)
{
    extern __shared__ bf16_t Wl[];
    const int b = blockIdx.x;
    const int tid = threadIdx.x;
    const int wv = tid >> 6;
    const int lane = tid & 63;
    const int q = lane >> 4;
    const int l = lane & 15;
    const int nn = wv * 16 + l;

    if (b < 64) {
        // ================= L0: layer-0 recurrence =================
        const int g0 = b;
        for (int c = tid; c < 64 * (LD0 / 8); c += 512) {
            int r = c / (LD0 / 8), off = (c % (LD0 / 8)) * 8;
            int u = r >> 2, gate = r & 3;
            *(bf16x8*)(Wl + r * ST0 + off) =
                *(const bf16x8*)(Wcat0 + (size_t)(gate * HID + g0 * 16 + u) * LD0 + off);
        }
        bf16_t* stage = Wl + 64 * ST0;
        __syncthreads();

        for (int t = 0; t < T_SEQ; ++t) {
            f32x4 acc[4] = {{0.f,0.f,0.f,0.f},{0.f,0.f,0.f,0.f},{0.f,0.f,0.f,0.f},{0.f,0.f,0.f,0.f}};
            // x panels: no dependency, compute BEFORE the wait
            {
                const bf16_t* X = xswz + (((size_t)t * 2) * 8) * 64 * 8;
#pragma unroll
                for (int p = 0; p < 2; ++p) {
                    bf16x8 bv = *(const bf16x8*)(X + (((size_t)p * 8 + wv) * 64 + lane) * 8);
#pragma unroll
                    for (int mt = 0; mt < 4; ++mt) {
                        bf16x8 av = *(const bf16x8*)(Wl + (mt * 16 + l) * ST0 + p * 32 + q * 8);
                        acc[mt] = __builtin_amdgcn_mfma_f32_16x16x32_bf16(av, bv, acc[mt], 0, 0, 0);
                    }
                }
            }
            // wait: f0 all >= t (own chain); fX all >= t-31 (mh0 slot reuse guard:
            // X1 reads mh0[t] at its step t). No pre-poll barrier needed.
            if (wv == 0) {
                const unsigned tA = (unsigned)t;
                const unsigned tB = (t >= DM) ? (unsigned)(t - (DM - 1)) : 0u;
                for (;;) {
                    bool ok = (ldcnt(&sync[F0 + lane]) >= tA)
                           && (ldcnt(&sync[FX + lane]) >= tB);
                    if (__all(ok)) break;
                    __builtin_amdgcn_s_sleep(1);
                }
            }
            __syncthreads();
            // h panels from mh0 slot (t-1): plain coalesced loads, 16-deep prefetch
            {
                const bf16_t* B = mh0 + (size_t)((t + DM - 1) & (DM - 1)) * HB;
                bf16x8 bb[16];
#pragma unroll
                for (int i = 0; i < 16; ++i)
                    bb[i] = *(const bf16x8*)(B + (((size_t)i * 8 + wv) * 64 + lane) * 8);
#pragma unroll
                for (int p = 0; p < 32; ++p) {
                    bf16x8 bv = bb[p & 15];
#pragma unroll
                    for (int mt = 0; mt < 4; ++mt) {
                        bf16x8 av = *(const bf16x8*)(Wl + (mt * 16 + l) * ST0 + FIN + p * 32 + q * 8);
                        acc[mt] = __builtin_amdgcn_mfma_f32_16x16x32_bf16(av, bv, acc[mt], 0, 0, 0);
                    }
                    if (p + 16 < 32)
                        bb[p & 15] = *(const bf16x8*)(B + (((size_t)(p + 16) * 8 + wv) * 64 + lane) * 8);
                }
            }
            // lane-local cell update -> stage
#pragma unroll
            for (int mt = 0; mt < 4; ++mt) {
                const int u = mt * 4 + q, j = g0 * 16 + u;
                float iv = sigm_f(acc[mt][0] + bias0[j]);
                float fv = sigm_f(acc[mt][1] + bias0[HID + j]);
                float gv = tanh_f(acc[mt][2] + bias0[2 * HID + j]);
                float ov = sigm_f(acc[mt][3] + bias0[3 * HID + j]);
                const size_t ci = (size_t)j * NB + nn;
                float cn = fv * c0[ci] + iv * gv;
                c0[ci] = cn;
                stage[nn * 16 + u] = (bf16_t)(ov * tanh_f(cn));
            }
            __syncthreads();
            if (tid < 256) {   // master write, swizzled, write-through
                const int n = tid >> 1, half = tid & 1;
                u64 v0 = *(const u64*)(stage + n * 16 + half * 8);
                u64 v1 = *(const u64*)(stage + n * 16 + half * 8 + 4);
                size_t unit = ((size_t)((g0 >> 1) * 8 + (n >> 4))) * 64
                              + ((g0 & 1) * 2 + half) * 16 + (n & 15);
                u64* dst = (u64*)(mh0 + (size_t)(t & (DM - 1)) * HB) + unit * 2;
                stw64(dst, v0); stw64(dst + 1, v1);
            }
            __syncthreads();   // all waves' master stores drained
            if (tid == 0) stw32(&sync[F0 + g0], (unsigned)(t + 1));
        }
    } else if (b < 128) {
        // ================= X1: W_ih1 @ h0[t] partials =================
        const int g = b - 64;   // 16 units: u_global in [g*16, g*16+16)
        for (int c = tid; c < 64 * 128; c += 512) {      // 64 rows x 128 octets
            int r = c >> 7, off = (c & 127) * 8;
            int u = r >> 2, gate = r & 3;
            *(bf16x8*)(Wl + r * STX + off) =
                *(const bf16x8*)(Wcat1 + (size_t)(gate * HID + g * 16 + u) * LD1 + off);
        }
        __syncthreads();

        for (int t = 0; t < T_SEQ; ++t) {
            // wait: f0 all >= t+1 (h0[t] ready); f1 all >= t-(DX-1) (ring guard)
            if (wv == 0) {
                const unsigned tA = (unsigned)(t + 1);
                const unsigned tC = (t >= DX) ? (unsigned)(t - (DX - 1)) : 0u;
                for (;;) {
                    bool ok = (ldcnt(&sync[F0 + lane]) >= tA)
                           && (ldcnt(&sync[F1 + lane]) >= tC)
                           && (ldcnt(&sync[F1 + 64 + lane]) >= tC);
                    if (__all(ok)) break;
                    __builtin_amdgcn_s_sleep(1);
                }
            }
            __syncthreads();
            f32x4 acc[4] = {{0.f,0.f,0.f,0.f},{0.f,0.f,0.f,0.f},{0.f,0.f,0.f,0.f},{0.f,0.f,0.f,0.f}};
            {
                const bf16_t* B = mh0 + (size_t)(t & (DM - 1)) * HB;
                bf16x8 bb[16];
#pragma unroll
                for (int i = 0; i < 16; ++i)
                    bb[i] = *(const bf16x8*)(B + (((size_t)i * 8 + wv) * 64 + lane) * 8);
#pragma unroll
                for (int p = 0; p < 32; ++p) {
                    bf16x8 bv = bb[p & 15];
#pragma unroll
                    for (int mt = 0; mt < 4; ++mt) {
                        bf16x8 av = *(const bf16x8*)(Wl + (mt * 16 + l) * STX + p * 32 + q * 8);
                        acc[mt] = __builtin_amdgcn_mfma_f32_16x16x32_bf16(av, bv, acc[mt], 0, 0, 0);
                    }
                    if (p + 16 < 32)
                        bb[p & 15] = *(const bf16x8*)(B + (((size_t)(p + 16) * 8 + wv) * 64 + lane) * 8);
                }
            }
            // scatter partials (f32, write-through): row = (u_loc*4 + gate)
            {
                float* P = x1r + (size_t)(t & (DX - 1)) * X1SLOT + (size_t)g * 64 * NB;
#pragma unroll
                for (int mt = 0; mt < 4; ++mt)
#pragma unroll
                    for (int j = 0; j < 4; ++j)
                        stwf(P + (size_t)((mt * 4 + q) * 4 + j) * NB + nn, acc[mt][j]);
            }
            __syncthreads();   // drain partial stores
            if (tid == 0) stw32(&sync[FX + g], (unsigned)(t + 1));
        }
    } else {
        // ================= L1: layer-1 recurrent half =================
        const int g1 = b - 128;  // 8 units: u_global in [g1*8, g1*8+8)
        for (int c = tid; c < 32 * 128; c += 512) {      // W_hh1 only (cols 1024..2047)
            int r = c >> 7, off = (c & 127) * 8;
            int u = r >> 2, gate = r & 3;
            *(bf16x8*)(Wl + r * STX + off) =
                *(const bf16x8*)(Wcat1 + (size_t)(gate * HID + g1 * 8 + u) * LD1 + HID + off);
        }
        bf16_t* stage = Wl + 32 * STX;
        __syncthreads();

        for (int t = 0; t < T_SEQ; ++t) {
            // wait: fX[g1>>1] >= t+1 (partials incl. h0[t] transitively ready);
            //       f1 all >= t (own chain + mh1 slot reuse guard)
            if (wv == 0) {
                const unsigned tA = (unsigned)(t + 1);
                const unsigned tO = (unsigned)t;
                const unsigned gx = (unsigned)(g1 >> 1);
                for (;;) {
                    bool ok = (ldcnt(&sync[FX + gx]) >= tA)
                           && (ldcnt(&sync[F1 + lane]) >= tO)
                           && (ldcnt(&sync[F1 + 64 + lane]) >= tO);
                    if (__all(ok)) break;
                    __builtin_amdgcn_s_sleep(1);
                }
            }
            __syncthreads();
            // acc init from X1 partials (8 x f32 per lane)
            f32x4 acc[2];
            {
                const float* P = x1r + (size_t)(t & (DX - 1)) * X1SLOT + (size_t)g1 * 32 * NB;
#pragma unroll
                for (int mt = 0; mt < 2; ++mt)
#pragma unroll
                    for (int j = 0; j < 4; ++j)
                        acc[mt][j] = P[(size_t)((mt * 4 + q) * 4 + j) * NB + nn];
            }
            // h1[t-1] recurrent half (K=1024)
            {
                const bf16_t* B1 = mh1 + (size_t)((t + DM - 1) & (DM - 1)) * HB;
                bf16x8 bb[16];
#pragma unroll
                for (int i = 0; i < 16; ++i)
                    bb[i] = *(const bf16x8*)(B1 + (((size_t)i * 8 + wv) * 64 + lane) * 8);
#pragma unroll
                for (int p = 0; p < 32; ++p) {
                    bf16x8 bv = bb[p & 15];
#pragma unroll
                    for (int mt = 0; mt < 2; ++mt) {
                        bf16x8 av = *(const bf16x8*)(Wl + (mt * 16 + l) * STX + p * 32 + q * 8);
                        acc[mt] = __builtin_amdgcn_mfma_f32_16x16x32_bf16(av, bv, acc[mt], 0, 0, 0);
                    }
                    if (p + 16 < 32)
                        bb[p & 15] = *(const bf16x8*)(B1 + (((size_t)(p + 16) * 8 + wv) * 64 + lane) * 8);
                }
            }
#pragma unroll
            for (int mt = 0; mt < 2; ++mt) {
                const int u = mt * 4 + q, j = g1 * 8 + u;
                float iv = sigm_f(acc[mt][0] + bias1[j]);
                float fv = sigm_f(acc[mt][1] + bias1[HID + j]);
                float gv = tanh_f(acc[mt][2] + bias1[2 * HID + j]);
                float ov = sigm_f(acc[mt][3] + bias1[3 * HID + j]);
                const size_t ci = (size_t)j * NB + nn;
                float cn = fv * c1[ci] + iv * gv;
                c1[ci] = cn;
                stage[nn * 8 + u] = (bf16_t)(ov * tanh_f(cn));
            }
            __syncthreads();
            if (tid < 128) {   // master write (swizzled, write-through)
                const int n = tid;
                u64 v0 = *(const u64*)(stage + n * 8);
                u64 v1 = *(const u64*)(stage + n * 8 + 4);
                size_t unit = ((size_t)((g1 >> 2) * 8 + (n >> 4))) * 64
                              + (g1 & 3) * 16 + (n & 15);
                u64* dst = (u64*)(mh1 + (size_t)(t & (DM - 1)) * HB) + unit * 2;
                stw64(dst, v0); stw64(dst + 1, v1);
            }
            __syncthreads();   // master stores drained
            if (tid == 0) stw32(&sync[F1 + g1], (unsigned)(t + 1));
            if (tid < 256) {   // h2 history AFTER flag (off the drain path;
                               // read only by fc_kernel after kernel end)
                const int n = tid >> 1, part = tid & 1;
                *(u64*)(h2buf + ((size_t)n * T_SEQ + t) * HID + g1 * 8 + part * 4) =
                    *(const u64*)(stage + n * 8 + part * 4);
            }
        }
    }
}

// Final FC: out[m][o] = h2[m][:] @ Wfc[o][:] + bfc[o], m = n*T + t.
__global__ __launch_bounds__(256) void fc_kernel(
    const bf16_t* __restrict__ h2buf, const bf16_t* __restrict__ Wfcb,
    const float* __restrict__ bfc, float* __restrict__ out)
{
    const int tid = threadIdx.x, wv = tid >> 6, lane = tid & 63;
    const int q = lane >> 4, l = lane & 15;
    const int m0 = blockIdx.x * 64 + wv * 16;
    const bf16_t* arow = h2buf + (size_t)(m0 + l) * HID + q * 8;
    const bf16_t* brow = Wfcb + (size_t)l * HID + q * 8;
    f32x4 acc[4] = {{0.f,0.f,0.f,0.f},{0.f,0.f,0.f,0.f},{0.f,0.f,0.f,0.f},{0.f,0.f,0.f,0.f}};
#pragma unroll 4
    for (int p = 0; p < 32; ++p) {
        bf16x8 av = *(const bf16x8*)(arow + p * 32);
#pragma unroll
        for (int ntile = 0; ntile < 4; ++ntile) {
            bf16x8 bv = *(const bf16x8*)(brow + (size_t)ntile * 16 * HID + p * 32);
            acc[ntile] = __builtin_amdgcn_mfma_f32_16x16x32_bf16(av, bv, acc[ntile], 0, 0, 0);
        }
    }
#pragma unroll
    for (int ntile = 0; ntile < 4; ++ntile) {
        float bv = bfc[ntile * 16 + l];
#pragma unroll
        for (int r = 0; r < 4; ++r)
            out[(size_t)(m0 + q * 4 + r) * 64 + ntile * 16 + l] = acc[ntile][r] + bv;
    }
}

extern "C" void kernel_launch(void* const* d_in, const int* in_sizes, int n_in,
                              void* d_out, int out_size, void* d_ws, size_t ws_size,
                              hipStream_t stream)
{
    const float* x    = (const float*)d_in[0];
    const float* Wih0 = (const float*)d_in[1];
    const float* Whh0 = (const float*)d_in[2];
    const float* bih0 = (const float*)d_in[3];
    const float* bhh0 = (const float*)d_in[4];
    const float* Wih1 = (const float*)d_in[5];
    const float* Whh1 = (const float*)d_in[6];
    const float* bih1 = (const float*)d_in[7];
    const float* bhh1 = (const float*)d_in[8];
    const float* Wfc  = (const float*)d_in[9];
    const float* bfc  = (const float*)d_in[10];
    float* out = (float*)d_out;

    char* ws = (char*)d_ws;
    size_t off = 0;
    auto alloc = [&](size_t bytes) -> void* {
        void* p = ws + off;
        off += (bytes + 255) & ~(size_t)255;
        return p;
    };
    bf16_t* Wcat0 = (bf16_t*)alloc((size_t)4096 * LD0 * 2);           // 8.9 MB
    bf16_t* Wcat1 = (bf16_t*)alloc((size_t)4096 * LD1 * 2);           // 16.8 MB
    bf16_t* xswz  = (bf16_t*)alloc((size_t)NB * T_SEQ * FIN * 2);     // 8.4 MB
    bf16_t* h2buf = (bf16_t*)alloc((size_t)NB * T_SEQ * HID * 2);     // 134 MB
    bf16_t* mh0   = (bf16_t*)alloc((size_t)DM * HB * 2);              // 8.4 MB
    bf16_t* mh1   = (bf16_t*)alloc((size_t)DM * HB * 2);              // 8.4 MB
    float*  x1r   = (float*)alloc((size_t)DX * X1SLOT * 4);           // 16.8 MB
    float*  c0    = (float*)alloc((size_t)HB * 4);
    float*  c1    = (float*)alloc((size_t)HB * 4);
    float*  bias0 = (float*)alloc(4096 * 4);
    float*  bias1 = (float*)alloc(4096 * 4);
    bf16_t* Wfcb  = (bf16_t*)alloc((size_t)64 * HID * 2);
    unsigned* syncp = (unsigned*)alloc(SYNC_N * 4);
    if (off > ws_size) return;

    hipFuncSetAttribute((const void*)lstm_persist,
                        hipFuncAttributeMaxDynamicSharedMemorySize, LDS_BYTES);

    prep_kernel<<<1024, 256, 0, stream>>>(x, Wih0, Whh0, bih0, bhh0,
                                          Wih1, Whh1, bih1, bhh1, Wfc,
                                          Wcat0, Wcat1, xswz, Wfcb,
                                          bias0, bias1, mh0, mh1,
                                          c0, c1, syncp);

    void* args[] = { (void*)&Wcat0, (void*)&Wcat1, (void*)&bias0, (void*)&bias1,
                     (void*)&xswz, (void*)&mh0, (void*)&mh1,
                     (void*)&c0, (void*)&c1, (void*)&h2buf, (void*)&x1r,
                     (void*)&syncp };
    hipLaunchCooperativeKernel((void*)lstm_persist, dim3(NBLK), dim3(512),
                               args, LDS_BYTES, stream);

    fc_kernel<<<(NB * T_SEQ) / 64, 256, 0, stream>>>(h2buf, Wfcb, bfc, out);
}